// Round 12
// baseline (59.561 us; speedup 1.0000x reference)
//
#include <hip/hip_runtime.h>
#include <hip/hip_bf16.h>

#define N_NODES 120000
#define F       64
#define NTILES  (N_NODES / 16)   // 7500 16-row tiles
#define GRID1   235              // persistent blocks for kernel 1

typedef __attribute__((ext_vector_type(8))) short bf16x8;   // 4 VGPRs
typedef __attribute__((ext_vector_type(4))) float f32x4;    // MFMA C/D

static __device__ __forceinline__ unsigned short f2bf(float x) {
    return __hip_bfloat16_raw(__float2bfloat16(x)).x;   // RNE
}
static __device__ __forceinline__ float u2f(unsigned int x) {
    return __uint_as_float(x);
}

// Kernel 1 (persistent MFMA GEMM, fused weight prep, operand-SWAPPED):
//   computes D = W^T · feat^T so each lane holds 4 CONSECUTIVE output columns
//   -> epilogue is 8-byte ushort4 stores instead of 32 scalar short stores.
//   T16 = bf16(feat @ theta_w); B16 = bf16(T + feat @ phi_w + theta_b + phi_b)
__global__ __launch_bounds__(256) void edgeconv_mfma(
    const float* __restrict__ feat,
    const float* __restrict__ theta_w,
    const float* __restrict__ phi_w,
    const float* __restrict__ theta_b,
    const float* __restrict__ phi_b,
    unsigned short* __restrict__ T16,
    unsigned short* __restrict__ B16)
{
    __shared__ unsigned short wfrag[16 * 64 * 8];   // [slot][lane][8] bf16 = 16 KB

    const int tid  = threadIdx.x;
    const int lane = tid & 63;
    const int wv   = tid >> 6;
    const int lo16 = lane & 15;
    const int hi8  = (lane >> 4) * 8;

    // Cooperative build: 1024 fragment entries, 4 per thread.
    // slot = (mat*4 + c)*2 + kb ; entry elem e = W[kb*32+(l>>4)*8+e][c*16+(l&15)]
    #pragma unroll
    for (int i = 0; i < 4; ++i) {
        const int eidx = tid + 256 * i;
        const int sl   = eidx >> 6, ln = eidx & 63;
        const int mat  = sl >> 3, c = (sl >> 1) & 3, kb = sl & 1;
        const float* W = mat ? phi_w : theta_w;
        const int k0   = kb * 32 + ((ln >> 4) * 8);
        const int col  = c * 16 + (ln & 15);
        bf16x8 v;
        #pragma unroll
        for (int e = 0; e < 8; ++e)
            v[e] = (short)f2bf(W[(k0 + e) * F + col]);
        ((bf16x8*)wfrag)[eidx] = v;
    }
    __syncthreads();

    // Each lane: 16 x ds_read_b128; fragments stay in VGPRs for all tiles.
    // As an A-operand this fragment IS (W block)^T: A[row=lane&15][k] = W[k][c*16+row].
    bf16x8 wt[4][2], wp[4][2];
    #pragma unroll
    for (int c = 0; c < 4; ++c) {
        #pragma unroll
        for (int kb = 0; kb < 2; ++kb) {
            wt[c][kb] = ((bf16x8*)wfrag)[(((c << 1) | kb)) * 64 + lane];
            wp[c][kb] = ((bf16x8*)wfrag)[(8 + ((c << 1) | kb)) * 64 + lane];
        }
    }

    // Hoisted bias: D-row = output col = c*16 + (lane>>4)*4 + rg.
    const int g4 = (lane >> 4) * 4;
    float bo[4][4];
    #pragma unroll
    for (int c = 0; c < 4; ++c)
        #pragma unroll
        for (int rg = 0; rg < 4; ++rg) {
            const int o = c * 16 + g4 + rg;
            bo[c][rg] = theta_b[o] + phi_b[o];
        }

    for (int tile = blockIdx.x * 4 + wv; tile < NTILES; tile += GRID1 * 4) {
        const int r0   = tile * 16;
        const int arow = r0 + lo16;

        // feat fragment (as B-operand = feat^T col-slice): elem e = feat[arow][k]
        const float4* f0 = (const float4*)(feat + arow * F + hi8);
        const float4* f1 = (const float4*)(feat + arow * F + 32 + hi8);
        float4 a0 = f0[0], a1 = f0[1];
        float4 a2 = f1[0], a3 = f1[1];
        bf16x8 afr0, afr1;
        afr0[0]=(short)f2bf(a0.x); afr0[1]=(short)f2bf(a0.y); afr0[2]=(short)f2bf(a0.z); afr0[3]=(short)f2bf(a0.w);
        afr0[4]=(short)f2bf(a1.x); afr0[5]=(short)f2bf(a1.y); afr0[6]=(short)f2bf(a1.z); afr0[7]=(short)f2bf(a1.w);
        afr1[0]=(short)f2bf(a2.x); afr1[1]=(short)f2bf(a2.y); afr1[2]=(short)f2bf(a2.z); afr1[3]=(short)f2bf(a2.w);
        afr1[4]=(short)f2bf(a3.x); afr1[5]=(short)f2bf(a3.y); afr1[6]=(short)f2bf(a3.z); afr1[7]=(short)f2bf(a3.w);

        f32x4 accT[4], accP[4];
        #pragma unroll
        for (int c = 0; c < 4; ++c) { accT[c] = (f32x4)(0.f); accP[c] = (f32x4)(0.f); }

        // D = A(W^T) x B(feat^T): D[row=o][col=node]
        #pragma unroll
        for (int c = 0; c < 4; ++c) {
            accT[c] = __builtin_amdgcn_mfma_f32_16x16x32_bf16(wt[c][0], afr0, accT[c], 0, 0, 0);
            accT[c] = __builtin_amdgcn_mfma_f32_16x16x32_bf16(wt[c][1], afr1, accT[c], 0, 0, 0);
            accP[c] = __builtin_amdgcn_mfma_f32_16x16x32_bf16(wp[c][0], afr0, accP[c], 0, 0, 0);
            accP[c] = __builtin_amdgcn_mfma_f32_16x16x32_bf16(wp[c][1], afr1, accP[c], 0, 0, 0);
        }

        // Epilogue: lane owns node r0+(lane&15), output cols c*16+g4+{0..3}
        // -> one 8B ushort4 store per (array, c).
        const int r = r0 + lo16;
        #pragma unroll
        for (int c = 0; c < 4; ++c) {
            const int obase = c * 16 + g4;
            ushort4 tv, bv;
            tv.x = f2bf(accT[c][0]); tv.y = f2bf(accT[c][1]);
            tv.z = f2bf(accT[c][2]); tv.w = f2bf(accT[c][3]);
            bv.x = f2bf(accT[c][0] + accP[c][0] + bo[c][0]);
            bv.y = f2bf(accT[c][1] + accP[c][1] + bo[c][1]);
            bv.z = f2bf(accT[c][2] + accP[c][2] + bo[c][2]);
            bv.w = f2bf(accT[c][3] + accP[c][3] + bo[c][3]);
            *(ushort4*)(T16 + r * F + obase) = tv;
            *(ushort4*)(B16 + r * F + obase) = bv;
        }
    }
}

// Kernel 2: out[v][o] = B[v][o] - min_k T[nbr[v][k]][o]
// 8 nodes/wave, 8 lanes/node, uint4 gathers (8 random 128B rows / instruction).
__global__ __launch_bounds__(256) void edgeconv_minmax(
    const int* __restrict__ nbr,              // [N,16] int32
    const unsigned short* __restrict__ T16,   // [N,64] bf16
    const unsigned short* __restrict__ B16,   // [N,64] bf16
    float* __restrict__ out)                  // [N,64] f32
{
    const int tid  = threadIdx.x;
    const int lane = tid & 63;
    const int wv   = tid >> 6;
    const int sub  = lane >> 3;      // node within wave, 0..7
    const int j    = lane & 7;       // lane covers cols 8j..8j+7 (16B)
    const int v    = blockIdx.x * 32 + wv * 8 + sub;

    // 16 neighbor indices (8 lanes/node same addr -> broadcast)
    const int4* nb4 = (const int4*)(nbr + v * 16);
    int4 i0 = nb4[0], i1 = nb4[1], i2 = nb4[2], i3 = nb4[3];
    int idx[16] = { i0.x, i0.y, i0.z, i0.w,
                    i1.x, i1.y, i1.z, i1.w,
                    i2.x, i2.y, i2.z, i2.w,
                    i3.x, i3.y, i3.z, i3.w };

    const char* tb = (const char*)T16 + (j << 4);

    // 16 independent 16B gathers per lane (issued before consumption).
    uint4 u[16];
    #pragma unroll
    for (int k = 0; k < 16; ++k)
        u[k] = *(const uint4*)(tb + (((unsigned int)idx[k]) << 7));

    // 8 running mins: even cols via <<16, odd cols via raw-as-f32
    // (raw dword's high half IS a valid f32; low-mantissa garbage <= 2^-8 rel).
    float mn[8];
    mn[0] = u2f(u[0].x << 16); mn[1] = u2f(u[0].x);
    mn[2] = u2f(u[0].y << 16); mn[3] = u2f(u[0].y);
    mn[4] = u2f(u[0].z << 16); mn[5] = u2f(u[0].z);
    mn[6] = u2f(u[0].w << 16); mn[7] = u2f(u[0].w);
    #pragma unroll
    for (int k = 1; k < 16; ++k) {
        mn[0] = fminf(mn[0], u2f(u[k].x << 16)); mn[1] = fminf(mn[1], u2f(u[k].x));
        mn[2] = fminf(mn[2], u2f(u[k].y << 16)); mn[3] = fminf(mn[3], u2f(u[k].y));
        mn[4] = fminf(mn[4], u2f(u[k].z << 16)); mn[5] = fminf(mn[5], u2f(u[k].z));
        mn[6] = fminf(mn[6], u2f(u[k].w << 16)); mn[7] = fminf(mn[7], u2f(u[k].w));
    }

    const uint4 bu = *(const uint4*)((const char*)B16 + (((unsigned int)v) << 7) + (j << 4));
    float4 r0, r1;
    r0.x = u2f(bu.x << 16)         - mn[0];
    r0.y = u2f(bu.x & 0xffff0000u) - mn[1];
    r0.z = u2f(bu.y << 16)         - mn[2];
    r0.w = u2f(bu.y & 0xffff0000u) - mn[3];
    r1.x = u2f(bu.z << 16)         - mn[4];
    r1.y = u2f(bu.z & 0xffff0000u) - mn[5];
    r1.z = u2f(bu.w << 16)         - mn[6];
    r1.w = u2f(bu.w & 0xffff0000u) - mn[7];

    float* op = out + v * F + j * 8;
    *(float4*)op       = r0;
    *(float4*)(op + 4) = r1;
}

extern "C" void kernel_launch(void* const* d_in, const int* in_sizes, int n_in,
                              void* d_out, int out_size, void* d_ws, size_t ws_size,
                              hipStream_t stream) {
    const float* feat    = (const float*)d_in[0];
    const int*   nbr     = (const int*)  d_in[1];
    const float* theta_w = (const float*)d_in[2];
    const float* theta_b = (const float*)d_in[3];
    const float* phi_w   = (const float*)d_in[4];
    const float* phi_b   = (const float*)d_in[5];
    float* out = (float*)d_out;

    unsigned short* T16 = (unsigned short*)d_ws;                   // 15.36 MB
    unsigned short* B16 = (unsigned short*)((char*)d_ws + 15360000);

    edgeconv_mfma<<<GRID1, 256, 0, stream>>>(feat, theta_w, phi_w,
                                             theta_b, phi_b, T16, B16);
    edgeconv_minmax<<<N_NODES / 32, 256, 0, stream>>>(nbr, T16, B16, out);
}

// Round 13
// 54.087 us; speedup vs baseline: 1.1012x; 1.1012x over previous
//
#include <hip/hip_runtime.h>
#include <hip/hip_bf16.h>

#define N_NODES 120000
#define F       64
#define NTILES  (N_NODES / 16)   // 7500 16-row tiles
#define GRID1   235              // persistent blocks for kernel 1

typedef __attribute__((ext_vector_type(8))) short bf16x8;   // 4 VGPRs
typedef __attribute__((ext_vector_type(4))) float f32x4;    // MFMA C/D

static __device__ __forceinline__ unsigned short f2bf(float x) {
    return __hip_bfloat16_raw(__float2bfloat16(x)).x;   // RNE
}
static __device__ __forceinline__ float u2f(unsigned int x) {
    return __uint_as_float(x);
}

// Kernel 1 (persistent MFMA GEMM, fused weight prep):
//   T16 = bf16(feat @ theta_w); B16 = bf16(T + feat @ phi_w + theta_b + phi_b)
// Fragment build is COOPERATIVE (256 threads fill the 16 KB wfrag layout in LDS,
// 16B vector writes), then each lane reads its 16 fragments once (ds_read_b128)
// and keeps them in registers across a grid-stride loop over row tiles.
// NOTE: mfma(feat, W) orientation kept deliberately — the swapped form
// (R12) scattered the epilogue stores across rows and regressed 11%.
__global__ __launch_bounds__(256) void edgeconv_mfma(
    const float* __restrict__ feat,
    const float* __restrict__ theta_w,
    const float* __restrict__ phi_w,
    const float* __restrict__ theta_b,
    const float* __restrict__ phi_b,
    unsigned short* __restrict__ T16,
    unsigned short* __restrict__ B16)
{
    __shared__ unsigned short wfrag[16 * 64 * 8];   // [slot][lane][8] bf16 = 16 KB

    const int tid  = threadIdx.x;
    const int lane = tid & 63;
    const int wv   = tid >> 6;
    const int lo16 = lane & 15;
    const int hi8  = (lane >> 4) * 8;

    // Cooperative build: 1024 fragment entries, 4 per thread.
    // slot = (mat*4 + c)*2 + kb ; entry elem e = W[kb*32+(l>>4)*8+e][c*16+(l&15)]
    #pragma unroll
    for (int i = 0; i < 4; ++i) {
        const int eidx = tid + 256 * i;
        const int sl   = eidx >> 6, ln = eidx & 63;
        const int mat  = sl >> 3, c = (sl >> 1) & 3, kb = sl & 1;
        const float* W = mat ? phi_w : theta_w;
        const int k0   = kb * 32 + ((ln >> 4) * 8);
        const int col  = c * 16 + (ln & 15);
        bf16x8 v;
        #pragma unroll
        for (int e = 0; e < 8; ++e)
            v[e] = (short)f2bf(W[(k0 + e) * F + col]);
        ((bf16x8*)wfrag)[eidx] = v;
    }
    __syncthreads();

    // Each lane: 16 x ds_read_b128, fragments live in VGPRs for all tiles.
    bf16x8 wt[4][2], wp[4][2];
    #pragma unroll
    for (int c = 0; c < 4; ++c) {
        #pragma unroll
        for (int kb = 0; kb < 2; ++kb) {
            wt[c][kb] = ((bf16x8*)wfrag)[(((c << 1) | kb)) * 64 + lane];
            wp[c][kb] = ((bf16x8*)wfrag)[(8 + ((c << 1) | kb)) * 64 + lane];
        }
    }

    // Hoisted bias per column.
    float bo[4];
    #pragma unroll
    for (int c = 0; c < 4; ++c)
        bo[c] = theta_b[c * 16 + lo16] + phi_b[c * 16 + lo16];

    const int rowbase = (lane >> 4) * 4;

    for (int tile = blockIdx.x * 4 + wv; tile < NTILES; tile += GRID1 * 4) {
        const int r0   = tile * 16;
        const int arow = r0 + lo16;

        const float4* f0 = (const float4*)(feat + arow * F + hi8);
        const float4* f1 = (const float4*)(feat + arow * F + 32 + hi8);
        float4 a0 = f0[0], a1 = f0[1];
        float4 a2 = f1[0], a3 = f1[1];
        bf16x8 afr0, afr1;
        afr0[0]=(short)f2bf(a0.x); afr0[1]=(short)f2bf(a0.y); afr0[2]=(short)f2bf(a0.z); afr0[3]=(short)f2bf(a0.w);
        afr0[4]=(short)f2bf(a1.x); afr0[5]=(short)f2bf(a1.y); afr0[6]=(short)f2bf(a1.z); afr0[7]=(short)f2bf(a1.w);
        afr1[0]=(short)f2bf(a2.x); afr1[1]=(short)f2bf(a2.y); afr1[2]=(short)f2bf(a2.z); afr1[3]=(short)f2bf(a2.w);
        afr1[4]=(short)f2bf(a3.x); afr1[5]=(short)f2bf(a3.y); afr1[6]=(short)f2bf(a3.z); afr1[7]=(short)f2bf(a3.w);

        f32x4 accT[4], accP[4];
        #pragma unroll
        for (int c = 0; c < 4; ++c) { accT[c] = (f32x4)(0.f); accP[c] = (f32x4)(0.f); }

        #pragma unroll
        for (int c = 0; c < 4; ++c) {
            accT[c] = __builtin_amdgcn_mfma_f32_16x16x32_bf16(afr0, wt[c][0], accT[c], 0, 0, 0);
            accT[c] = __builtin_amdgcn_mfma_f32_16x16x32_bf16(afr1, wt[c][1], accT[c], 0, 0, 0);
            accP[c] = __builtin_amdgcn_mfma_f32_16x16x32_bf16(afr0, wp[c][0], accP[c], 0, 0, 0);
            accP[c] = __builtin_amdgcn_mfma_f32_16x16x32_bf16(afr1, wp[c][1], accP[c], 0, 0, 0);
        }

        // Epilogue: D layout col = lane&15, row = (lane>>4)*4 + reg.
        // Per (c,rg) the 16 lanes of a group write one contiguous 32B segment.
        #pragma unroll
        for (int c = 0; c < 4; ++c) {
            const int col = c * 16 + lo16;
            #pragma unroll
            for (int rg = 0; rg < 4; ++rg) {
                const int r = r0 + rowbase + rg;
                const float t = accT[c][rg];
                T16[r * F + col] = f2bf(t);
                B16[r * F + col] = f2bf(t + accP[c][rg] + bo[c]);
            }
        }
    }
}

// Kernel 2: out[v][o] = B[v][o] - min_k T[nbr[v][k]][o]
// 8 nodes/wave, 8 lanes/node, uint4 gathers (8 random 128B rows / instruction).
__global__ __launch_bounds__(256) void edgeconv_minmax(
    const int* __restrict__ nbr,              // [N,16] int32
    const unsigned short* __restrict__ T16,   // [N,64] bf16
    const unsigned short* __restrict__ B16,   // [N,64] bf16
    float* __restrict__ out)                  // [N,64] f32
{
    const int tid  = threadIdx.x;
    const int lane = tid & 63;
    const int wv   = tid >> 6;
    const int sub  = lane >> 3;      // node within wave, 0..7
    const int j    = lane & 7;       // lane covers cols 8j..8j+7 (16B)
    const int v    = blockIdx.x * 32 + wv * 8 + sub;

    // 16 neighbor indices (8 lanes/node same addr -> broadcast)
    const int4* nb4 = (const int4*)(nbr + v * 16);
    int4 i0 = nb4[0], i1 = nb4[1], i2 = nb4[2], i3 = nb4[3];
    int idx[16] = { i0.x, i0.y, i0.z, i0.w,
                    i1.x, i1.y, i1.z, i1.w,
                    i2.x, i2.y, i2.z, i2.w,
                    i3.x, i3.y, i3.z, i3.w };

    const char* tb = (const char*)T16 + (j << 4);

    // 16 independent 16B gathers per lane (issued before consumption).
    uint4 u[16];
    #pragma unroll
    for (int k = 0; k < 16; ++k)
        u[k] = *(const uint4*)(tb + (((unsigned int)idx[k]) << 7));

    // 8 running mins: even cols via <<16, odd cols via raw-as-f32
    // (raw dword's high half IS a valid f32; low-mantissa garbage <= 2^-8 rel).
    float mn[8];
    mn[0] = u2f(u[0].x << 16); mn[1] = u2f(u[0].x);
    mn[2] = u2f(u[0].y << 16); mn[3] = u2f(u[0].y);
    mn[4] = u2f(u[0].z << 16); mn[5] = u2f(u[0].z);
    mn[6] = u2f(u[0].w << 16); mn[7] = u2f(u[0].w);
    #pragma unroll
    for (int k = 1; k < 16; ++k) {
        mn[0] = fminf(mn[0], u2f(u[k].x << 16)); mn[1] = fminf(mn[1], u2f(u[k].x));
        mn[2] = fminf(mn[2], u2f(u[k].y << 16)); mn[3] = fminf(mn[3], u2f(u[k].y));
        mn[4] = fminf(mn[4], u2f(u[k].z << 16)); mn[5] = fminf(mn[5], u2f(u[k].z));
        mn[6] = fminf(mn[6], u2f(u[k].w << 16)); mn[7] = fminf(mn[7], u2f(u[k].w));
    }

    const uint4 bu = *(const uint4*)((const char*)B16 + (((unsigned int)v) << 7) + (j << 4));
    float4 r0, r1;
    r0.x = u2f(bu.x << 16)         - mn[0];
    r0.y = u2f(bu.x & 0xffff0000u) - mn[1];
    r0.z = u2f(bu.y << 16)         - mn[2];
    r0.w = u2f(bu.y & 0xffff0000u) - mn[3];
    r1.x = u2f(bu.z << 16)         - mn[4];
    r1.y = u2f(bu.z & 0xffff0000u) - mn[5];
    r1.z = u2f(bu.w << 16)         - mn[6];
    r1.w = u2f(bu.w & 0xffff0000u) - mn[7];

    float* op = out + v * F + j * 8;
    *(float4*)op       = r0;
    *(float4*)(op + 4) = r1;
}

extern "C" void kernel_launch(void* const* d_in, const int* in_sizes, int n_in,
                              void* d_out, int out_size, void* d_ws, size_t ws_size,
                              hipStream_t stream) {
    const float* feat    = (const float*)d_in[0];
    const int*   nbr     = (const int*)  d_in[1];
    const float* theta_w = (const float*)d_in[2];
    const float* theta_b = (const float*)d_in[3];
    const float* phi_w   = (const float*)d_in[4];
    const float* phi_b   = (const float*)d_in[5];
    float* out = (float*)d_out;

    unsigned short* T16 = (unsigned short*)d_ws;                   // 15.36 MB
    unsigned short* B16 = (unsigned short*)((char*)d_ws + 15360000);

    edgeconv_mfma<<<GRID1, 256, 0, stream>>>(feat, theta_w, phi_w,
                                             theta_b, phi_b, T16, B16);
    edgeconv_minmax<<<N_NODES / 32, 256, 0, stream>>>(nbr, T16, B16, out);
}